// Round 2
// baseline (103.669 us; speedup 1.0000x reference)
//
#include <hip/hip_runtime.h>
#include <math.h>

// Additive (Bahdanau) attention. N=4, NQ=256, NV=512, NE=256, fp32.
// R10: phase1 VALU/trans pipe balance (6/8 pairs paired, 2/8 unpaired ->
// VALU 352 vs trans 320 cyc per 16e granule), EC float4-quad layout (half the
// load-issue/addr ops), prob-normalize elided (folded into heads scale),
// exp2-folded softmax, float4 out-GEMM. Model: dur = ~83us harness fills +
// ~16.6us ours (phase1 5.5 VALU-bound, PV 3.7 L2-bound, gemm 2, prep 3).
#define N_B   4
#define NQ_   256
#define NV_   512
#define NE_   256

// 2*log2(e): sigma-term = rcp(1 + exp2(s*q)*exp2(s*c))
#define QSCALE 2.8853900817779268f
#define QTF 4

__device__ __forceinline__ float wave_reduce_sum(float v) {
#pragma unroll
    for (int m = 32; m > 0; m >>= 1) v += __shfl_xor(v, m, 64);
    return v;
}

// ---- prep (144 blocks):
//   b 0..127  : EC quad-interleaved transpose+exp2 of C:
//               ECq[n][e/4][v] = float4{exp2(s*C[v][4e..4e+3])}
//   b 128..143: WRT[e][e'] = WR[e'][e]
__global__ __launch_bounds__(256) void prep_kernel(const float* __restrict__ C,
                                                   const float* __restrict__ W,
                                                   float* __restrict__ EC,
                                                   float* __restrict__ WT) {
    __shared__ float tile[64][65];
    const int b = blockIdx.x;
    if (b < 128) {
        const int n  = b >> 5;
        const int e0 = ((b >> 3) & 3) * 64;
        const int v0 = (b & 7) * 64;
        const float* src = C + ((size_t)n * NV_ + v0) * NE_ + e0;
        const int c4 = (threadIdx.x & 15) * 4;
        const int r  = threadIdx.x >> 4;
#pragma unroll
        for (int it = 0; it < 4; ++it) {
            const int vl = it * 16 + r;
            const float4 x = *(const float4*)(src + (size_t)vl * NE_ + c4);
            tile[vl][c4 + 0] = __builtin_amdgcn_exp2f(x.x * QSCALE);
            tile[vl][c4 + 1] = __builtin_amdgcn_exp2f(x.y * QSCALE);
            tile[vl][c4 + 2] = __builtin_amdgcn_exp2f(x.z * QSCALE);
            tile[vl][c4 + 3] = __builtin_amdgcn_exp2f(x.w * QSCALE);
        }
        __syncthreads();
        const int vcol = threadIdx.x & 63, row4 = threadIdx.x >> 6;
        float4* dst = (float4*)EC + ((size_t)n * (NE_ / 4) + (e0 >> 2)) * NV_ + v0;
#pragma unroll
        for (int rr = 0; rr < 4; ++rr) {
            const int qd = rr * 4 + row4;   // local quad 0..15
            dst[(size_t)qd * NV_ + vcol] =
                make_float4(tile[vcol][4 * qd + 0], tile[vcol][4 * qd + 1],
                            tile[vcol][4 * qd + 2], tile[vcol][4 * qd + 3]);
        }
    } else {
        const int bb = b - 128;
        const int r0 = (bb >> 2) * 64, c0 = (bb & 3) * 64;
        const int col = threadIdx.x & 63, row4 = threadIdx.x >> 6;
        const float* src = W + (size_t)r0 * NE_ + c0;
#pragma unroll
        for (int r = 0; r < 16; ++r) {
            const int rl = row4 + r * 4;
            tile[rl][col] = src[(size_t)rl * NE_ + col];
        }
        __syncthreads();
        float* dst = WT + (size_t)c0 * NE_ + r0;
#pragma unroll
        for (int r = 0; r < 16; ++r) {
            const int cl = row4 + r * 4;
            dst[(size_t)cl * NE_ + col] = tile[col][cl];
        }
    }
}

#define FMA4(h, p, m)                  \
    h.x = fmaf(p, m.x, h.x);           \
    h.y = fmaf(p, m.y, h.y);           \
    h.z = fmaf(p, m.z, h.z);           \
    h.w = fmaf(p, m.w, h.w)

// paired sigma-pair over (e, e+1): w0/a + w1/b = (w0*b+w1*a)*rcp(a*b);
// a,b in [1, 2^30] -> ab < 2^60, fp32-safe.
#define PAIR(c0, c1, ebase) {                                        \
    const float4 qa = *(const float4*)s_q[(ebase)];                  \
    const float4 qb = *(const float4*)s_q[(ebase) + 1];              \
    const float w0 = s_w[(ebase)], w1 = s_w[(ebase) + 1];            \
    { const float a = fmaf((c0), qa.x, 1.0f);                        \
      const float b = fmaf((c1), qb.x, 1.0f);                        \
      const float num = fmaf(w1, a, w0 * b);                         \
      acc0 = fmaf(num, __builtin_amdgcn_rcpf(a * b), acc0); }        \
    { const float a = fmaf((c0), qa.y, 1.0f);                        \
      const float b = fmaf((c1), qb.y, 1.0f);                        \
      const float num = fmaf(w1, a, w0 * b);                         \
      acc1 = fmaf(num, __builtin_amdgcn_rcpf(a * b), acc1); }        \
    { const float a = fmaf((c0), qa.z, 1.0f);                        \
      const float b = fmaf((c1), qb.z, 1.0f);                        \
      const float num = fmaf(w1, a, w0 * b);                         \
      acc2 = fmaf(num, __builtin_amdgcn_rcpf(a * b), acc2); }        \
    { const float a = fmaf((c0), qa.w, 1.0f);                        \
      const float b = fmaf((c1), qb.w, 1.0f);                        \
      const float num = fmaf(w1, a, w0 * b);                         \
      acc3 = fmaf(num, __builtin_amdgcn_rcpf(a * b), acc3); }        \
}

// unpaired sigma elem: acc += w * rcp(1 + c*q)  (2 VALU + 1 trans per q)
#define UNP(c, ebase) {                                              \
    const float4 qa = *(const float4*)s_q[(ebase)];                  \
    const float w = s_w[(ebase)];                                    \
    acc0 = fmaf(w, __builtin_amdgcn_rcpf(fmaf((c), qa.x, 1.0f)), acc0); \
    acc1 = fmaf(w, __builtin_amdgcn_rcpf(fmaf((c), qa.y, 1.0f)), acc1); \
    acc2 = fmaf(w, __builtin_amdgcn_rcpf(fmaf((c), qa.z, 1.0f)), acc2); \
    acc3 = fmaf(w, __builtin_amdgcn_rcpf(fmaf((c), qa.w, 1.0f)), acc3); \
}

__global__ __launch_bounds__(1024) void fused_attn(
    const float* __restrict__ Q,    // [N][NQ][NE]
    const float* __restrict__ EC,   // [N][NE/4][NV] float4-quad exp2(s*C^T)
    const float* __restrict__ WL,   // [NE]
    const float* __restrict__ M,    // [N][NV][NE]
    const float* __restrict__ TEMP,
    const float* __restrict__ WRT,  // [NE][NE] = WR^T
    const float* __restrict__ BR,   // [NE]
    float* __restrict__ OUT)        // [N][NQ][NE]
{
    const int n   = blockIdx.y;
    const int q0  = blockIdx.x * QTF;
    const int tid = threadIdx.x;
    const int wv  = tid >> 6, ln = tid & 63;

    __shared__ __align__(16) float s_q[NE_][QTF];        // 4 KB  exp2(s*q)
    __shared__ __align__(16) float s_w[NE_];             // 1 KB
    __shared__ __align__(16) float s_prob[QTF][NV_];     // 8 KB (UNnormalized)
    __shared__ __align__(16) float s_sp[QTF][NV_];       // 8 KB e-half S partials
    __shared__ __align__(16) float s_part[16][QTF][NE_]; // 64 KB PV partials
    __shared__ __align__(16) float s_heads[QTF][NE_];    // 4 KB
    __shared__ __align__(16) float4 s_gp4[3][QTF][64];   // 12 KB gemm partials
    __shared__ float s_sum[QTF][8];

    // ---- preload EQ = exp2(QSCALE*Q) and w ----
    {
        const int e = tid & 255;
        const int g = tid >> 8;          // q row 0..3
        s_q[e][g] = __builtin_amdgcn_exp2f(
            Q[((size_t)n * NQ_ + q0 + g) * NE_ + e] * QSCALE);
        if (g == 0) s_w[e] = WL[e];
    }
    __syncthreads();

    // ---- phase 1: S[q][v] = sum_e w[e]*sigma; e split across halves.
    // 16-e granules: 3 float4 paired (6 pairs) + 1 float4 unpaired (4 elems)
    // -> VALU 352 cyc vs trans 320 cyc per granule: pipes balanced.
    const int v  = tid & 511;
    const int eh = tid >> 9;
    float acc0 = 0.f, acc1 = 0.f, acc2 = 0.f, acc3 = 0.f;
    {
        const float4* ecq =
            (const float4*)EC + ((size_t)n * (NE_ / 4) + eh * 32) * NV_ + v;
#pragma unroll 2
        for (int g = 0; g < 8; ++g) {
            const int qb = g * 4;
#pragma unroll
            for (int j = 0; j < 3; ++j) {
                const float4 c4 = ecq[(size_t)(qb + j) * NV_];
                const int e = eh * 128 + (qb + j) * 4;
                PAIR(c4.x, c4.y, e);
                PAIR(c4.z, c4.w, e + 2);
            }
            {
                const float4 c4 = ecq[(size_t)(qb + 3) * NV_];
                const int e = eh * 128 + (qb + 3) * 4;
                UNP(c4.x, e);
                UNP(c4.y, e + 1);
                UNP(c4.z, e + 2);
                UNP(c4.w, e + 3);
            }
        }
    }
    if (eh) {
        s_sp[0][v] = acc0; s_sp[1][v] = acc1;
        s_sp[2][v] = acc2; s_sp[3][v] = acc3;
    }
    __syncthreads();

    // ---- phase 2: unnormalized softmax numerators (threads 0..511).
    // max-sub elided: |S| <= sum|w| ~13 -> exponent |l|*2log2e <= ~40, safe.
    if (!eh) {
        const float sE = -2.8853900817779268f / TEMP[0];  // -2*log2(e)/temp
        const float p0 = __builtin_amdgcn_exp2f((acc0 + s_sp[0][v]) * sE);
        const float p1 = __builtin_amdgcn_exp2f((acc1 + s_sp[1][v]) * sE);
        const float p2 = __builtin_amdgcn_exp2f((acc2 + s_sp[2][v]) * sE);
        const float p3 = __builtin_amdgcn_exp2f((acc3 + s_sp[3][v]) * sE);
        s_prob[0][v] = p0; s_prob[1][v] = p1;
        s_prob[2][v] = p2; s_prob[3][v] = p3;
        const float r0 = wave_reduce_sum(p0);
        const float r1 = wave_reduce_sum(p1);
        const float r2 = wave_reduce_sum(p2);
        const float r3 = wave_reduce_sum(p3);
        if (ln == 0) {
            s_sum[0][wv] = r0; s_sum[1][wv] = r1;
            s_sum[2][wv] = r2; s_sum[3][wv] = r3;
        }
    }
    __syncthreads();

    // ---- phase 3: PV on unnormalized probs. 16 waves x 32 v; lane = e-quad
    {
        const float4* M4 = (const float4*)(M + (size_t)n * NV_ * NE_);
        float4 h0 = make_float4(0.f, 0.f, 0.f, 0.f);
        float4 h1 = h0, h2 = h0, h3 = h0;
        const int v0w = wv * 32;
#pragma unroll 2
        for (int vb = v0w; vb < v0w + 32; vb += 4) {
            const float4 pq0 = *(const float4*)&s_prob[0][vb];
            const float4 pq1 = *(const float4*)&s_prob[1][vb];
            const float4 pq2 = *(const float4*)&s_prob[2][vb];
            const float4 pq3 = *(const float4*)&s_prob[3][vb];
            float4 mm;
            mm = M4[(size_t)(vb + 0) * (NE_ / 4) + ln];
            FMA4(h0, pq0.x, mm); FMA4(h1, pq1.x, mm);
            FMA4(h2, pq2.x, mm); FMA4(h3, pq3.x, mm);
            mm = M4[(size_t)(vb + 1) * (NE_ / 4) + ln];
            FMA4(h0, pq0.y, mm); FMA4(h1, pq1.y, mm);
            FMA4(h2, pq2.y, mm); FMA4(h3, pq3.y, mm);
            mm = M4[(size_t)(vb + 2) * (NE_ / 4) + ln];
            FMA4(h0, pq0.z, mm); FMA4(h1, pq1.z, mm);
            FMA4(h2, pq2.z, mm); FMA4(h3, pq3.z, mm);
            mm = M4[(size_t)(vb + 3) * (NE_ / 4) + ln];
            FMA4(h0, pq0.w, mm); FMA4(h1, pq1.w, mm);
            FMA4(h2, pq2.w, mm); FMA4(h3, pq3.w, mm);
        }
        ((float4*)s_part[wv][0])[ln] = h0;
        ((float4*)s_part[wv][1])[ln] = h1;
        ((float4*)s_part[wv][2])[ln] = h2;
        ((float4*)s_part[wv][3])[ln] = h3;
    }
    __syncthreads();

    // ---- reduce 16 PV partials, fold 1/sum (softmax denom) + leaky_relu ----
    {
        const int t = tid >> 8, e = tid & 255;
        float s = 0.f;
#pragma unroll
        for (int w = 0; w < 16; ++w) s += s_part[w][t][e];
        float tot = 0.f;
#pragma unroll
        for (int w = 0; w < 8; ++w) tot += s_sum[t][w];
        const float hv = s * (1.0f / tot);
        s_heads[t][e] = (hv > 0.0f) ? hv : 0.01f * hv;
    }
    __syncthreads();

    // ---- out GEMM: thread = (q, e-quarter k, ep-quad). float4 WRT loads,
    //      wave-uniform k -> coalesced 1KB/load; 4-way e-merge via LDS ----
    {
        const int q   = tid >> 8;
        const int k   = (tid >> 6) & 3;
        const int epq = tid & 63;
        const float4* wr4 = (const float4*)WRT + epq;
        float4 a = make_float4(0.f, 0.f, 0.f, 0.f);
        const int e0g = k * 64;
#pragma unroll 8
        for (int e = e0g; e < e0g + 64; ++e) {
            const float h = s_heads[q][e];
            const float4 w4 = wr4[(size_t)e * (NE_ / 4)];
            FMA4(a, h, w4);
        }
        if (k) s_gp4[k - 1][q][epq] = a;
        __syncthreads();
        if (k == 0) {
#pragma unroll
            for (int kk = 0; kk < 3; ++kk) {
                const float4 p = s_gp4[kk][q][epq];
                a.x += p.x; a.y += p.y; a.z += p.z; a.w += p.w;
            }
            const float4 b4 = ((const float4*)BR)[epq];
            a.x += b4.x; a.y += b4.y; a.z += b4.z; a.w += b4.w;
            ((float4*)OUT)[((size_t)n * NQ_ + q0 + q) * (NE_ / 4) + epq] = a;
        }
    }
}

extern "C" void kernel_launch(void* const* d_in, const int* in_sizes, int n_in,
                              void* d_out, int out_size, void* d_ws, size_t ws_size,
                              hipStream_t stream) {
    const float* Q  = (const float*)d_in[0];
    const float* C  = (const float*)d_in[1];
    const float* M  = (const float*)d_in[2];
    const float* WL = (const float*)d_in[3];
    // d_in[4] = b_logit: softmax shift-invariant -> unused.
    const float* T  = (const float*)d_in[5];
    const float* WR = (const float*)d_in[6];
    const float* BR = (const float*)d_in[7];
    float* OUT = (float*)d_out;

    float* EC  = (float*)d_ws;                   // N*NE*NV floats (quads) = 2 MB
    float* WRT = EC + (size_t)N_B * NE_ * NV_;   // NE*NE = 256 KB

    prep_kernel<<<dim3(144), 256, 0, stream>>>(C, WR, EC, WRT);

    dim3 gf(NQ_ / QTF, N_B);
    fused_attn<<<gf, 1024, 0, stream>>>(Q, EC, WL, M, T, WRT, BR, OUT);
}

// Round 3
// 101.565 us; speedup vs baseline: 1.0207x; 1.0207x over previous
//
#include <hip/hip_runtime.h>
#include <math.h>

// Additive (Bahdanau) attention. N=4, NQ=256, NV=512, NE=256, fp32.
// R11: A/B isolating R10's regression. Phase1 reverted to ALL-PAIRED rcp
// (R9-proven; R10's 6-paired/2-unpaired mix is the regression suspect under
// an additive trans-issue model: 672 vs 640 issue-cyc per granule). Keeps
// R10's orthogonal wins: float4 EC quad layout, normalize-elide (denom folded
// into heads), exp2-folded softmax, float4 out-GEMM, float4 prep.
// Model: dur = ~83us harness poison fills + ours (phase1 ~5-8us VALU/trans,
// PV ~3.5us L2-stream, gemm ~1.5, prep ~2.5, barriers/ramp ~2).
#define N_B   4
#define NQ_   256
#define NV_   512
#define NE_   256

// 2*log2(e): sigma-term = rcp(1 + exp2(s*q)*exp2(s*c))
#define QSCALE 2.8853900817779268f
#define QTF 4

__device__ __forceinline__ float wave_reduce_sum(float v) {
#pragma unroll
    for (int m = 32; m > 0; m >>= 1) v += __shfl_xor(v, m, 64);
    return v;
}

// ---- prep (144 blocks):
//   b 0..127  : EC quad-interleaved transpose+exp2 of C:
//               ECq[n][e/4][v] = float4{exp2(s*C[v][4e..4e+3])}
//   b 128..143: WRT[e][e'] = WR[e'][e]
__global__ __launch_bounds__(256) void prep_kernel(const float* __restrict__ C,
                                                   const float* __restrict__ W,
                                                   float* __restrict__ EC,
                                                   float* __restrict__ WT) {
    __shared__ float tile[64][65];
    const int b = blockIdx.x;
    if (b < 128) {
        const int n  = b >> 5;
        const int e0 = ((b >> 3) & 3) * 64;
        const int v0 = (b & 7) * 64;
        const float* src = C + ((size_t)n * NV_ + v0) * NE_ + e0;
        const int c4 = (threadIdx.x & 15) * 4;
        const int r  = threadIdx.x >> 4;
#pragma unroll
        for (int it = 0; it < 4; ++it) {
            const int vl = it * 16 + r;
            const float4 x = *(const float4*)(src + (size_t)vl * NE_ + c4);
            tile[vl][c4 + 0] = __builtin_amdgcn_exp2f(x.x * QSCALE);
            tile[vl][c4 + 1] = __builtin_amdgcn_exp2f(x.y * QSCALE);
            tile[vl][c4 + 2] = __builtin_amdgcn_exp2f(x.z * QSCALE);
            tile[vl][c4 + 3] = __builtin_amdgcn_exp2f(x.w * QSCALE);
        }
        __syncthreads();
        const int vcol = threadIdx.x & 63, row4 = threadIdx.x >> 6;
        float4* dst = (float4*)EC + ((size_t)n * (NE_ / 4) + (e0 >> 2)) * NV_ + v0;
#pragma unroll
        for (int rr = 0; rr < 4; ++rr) {
            const int qd = rr * 4 + row4;   // local quad 0..15
            dst[(size_t)qd * NV_ + vcol] =
                make_float4(tile[vcol][4 * qd + 0], tile[vcol][4 * qd + 1],
                            tile[vcol][4 * qd + 2], tile[vcol][4 * qd + 3]);
        }
    } else {
        const int bb = b - 128;
        const int r0 = (bb >> 2) * 64, c0 = (bb & 3) * 64;
        const int col = threadIdx.x & 63, row4 = threadIdx.x >> 6;
        const float* src = W + (size_t)r0 * NE_ + c0;
#pragma unroll
        for (int r = 0; r < 16; ++r) {
            const int rl = row4 + r * 4;
            tile[rl][col] = src[(size_t)rl * NE_ + col];
        }
        __syncthreads();
        float* dst = WT + (size_t)c0 * NE_ + r0;
#pragma unroll
        for (int r = 0; r < 16; ++r) {
            const int cl = row4 + r * 4;
            dst[(size_t)cl * NE_ + col] = tile[col][cl];
        }
    }
}

#define FMA4(h, p, m)                  \
    h.x = fmaf(p, m.x, h.x);           \
    h.y = fmaf(p, m.y, h.y);           \
    h.z = fmaf(p, m.z, h.z);           \
    h.w = fmaf(p, m.w, h.w)

// paired sigma-pair over (e, e+1): w0/a + w1/b = (w0*b+w1*a)*rcp(a*b);
// a,b in [1, 2^30] -> ab < 2^60, fp32-safe. 6 VALU + 1 trans per q.
#define PAIR(c0, c1, ebase) {                                        \
    const float4 qa = *(const float4*)s_q[(ebase)];                  \
    const float4 qb = *(const float4*)s_q[(ebase) + 1];              \
    const float w0 = s_w[(ebase)], w1 = s_w[(ebase) + 1];            \
    { const float a = fmaf((c0), qa.x, 1.0f);                        \
      const float b = fmaf((c1), qb.x, 1.0f);                        \
      const float num = fmaf(w1, a, w0 * b);                         \
      acc0 = fmaf(num, __builtin_amdgcn_rcpf(a * b), acc0); }        \
    { const float a = fmaf((c0), qa.y, 1.0f);                        \
      const float b = fmaf((c1), qb.y, 1.0f);                        \
      const float num = fmaf(w1, a, w0 * b);                         \
      acc1 = fmaf(num, __builtin_amdgcn_rcpf(a * b), acc1); }        \
    { const float a = fmaf((c0), qa.z, 1.0f);                        \
      const float b = fmaf((c1), qb.z, 1.0f);                        \
      const float num = fmaf(w1, a, w0 * b);                         \
      acc2 = fmaf(num, __builtin_amdgcn_rcpf(a * b), acc2); }        \
    { const float a = fmaf((c0), qa.w, 1.0f);                        \
      const float b = fmaf((c1), qb.w, 1.0f);                        \
      const float num = fmaf(w1, a, w0 * b);                         \
      acc3 = fmaf(num, __builtin_amdgcn_rcpf(a * b), acc3); }        \
}

__global__ __launch_bounds__(1024) void fused_attn(
    const float* __restrict__ Q,    // [N][NQ][NE]
    const float* __restrict__ EC,   // [N][NE/4][NV] float4-quad exp2(s*C^T)
    const float* __restrict__ WL,   // [NE]
    const float* __restrict__ M,    // [N][NV][NE]
    const float* __restrict__ TEMP,
    const float* __restrict__ WRT,  // [NE][NE] = WR^T
    const float* __restrict__ BR,   // [NE]
    float* __restrict__ OUT)        // [N][NQ][NE]
{
    const int n   = blockIdx.y;
    const int q0  = blockIdx.x * QTF;
    const int tid = threadIdx.x;
    const int wv  = tid >> 6, ln = tid & 63;

    __shared__ __align__(16) float s_q[NE_][QTF];        // 4 KB  exp2(s*q)
    __shared__ __align__(16) float s_w[NE_];             // 1 KB
    __shared__ __align__(16) float s_prob[QTF][NV_];     // 8 KB (UNnormalized)
    __shared__ __align__(16) float s_sp[QTF][NV_];       // 8 KB e-half S partials
    __shared__ __align__(16) float s_part[16][QTF][NE_]; // 64 KB PV partials
    __shared__ __align__(16) float s_heads[QTF][NE_];    // 4 KB
    __shared__ __align__(16) float4 s_gp4[3][QTF][64];   // 12 KB gemm partials
    __shared__ float s_sum[QTF][8];

    // ---- preload EQ = exp2(QSCALE*Q) and w ----
    {
        const int e = tid & 255;
        const int g = tid >> 8;          // q row 0..3
        s_q[e][g] = __builtin_amdgcn_exp2f(
            Q[((size_t)n * NQ_ + q0 + g) * NE_ + e] * QSCALE);
        if (g == 0) s_w[e] = WL[e];
    }
    __syncthreads();

    // ---- phase 1: S[q][v] = sum_e w[e]*sigma; e split across halves.
    // ALL-PAIRED (R9-proven): 2 PAIRs per float4 EC quad.
    const int v  = tid & 511;
    const int eh = tid >> 9;
    float acc0 = 0.f, acc1 = 0.f, acc2 = 0.f, acc3 = 0.f;
    {
        const float4* ecq =
            (const float4*)EC + ((size_t)n * (NE_ / 4) + eh * 32) * NV_ + v;
#pragma unroll 4
        for (int qd = 0; qd < 32; ++qd) {
            const float4 c4 = ecq[(size_t)qd * NV_];
            const int e = eh * 128 + qd * 4;
            PAIR(c4.x, c4.y, e);
            PAIR(c4.z, c4.w, e + 2);
        }
    }
    if (eh) {
        s_sp[0][v] = acc0; s_sp[1][v] = acc1;
        s_sp[2][v] = acc2; s_sp[3][v] = acc3;
    }
    __syncthreads();

    // ---- phase 2: unnormalized softmax numerators (threads 0..511).
    // max-sub elided: |S| <= sum|w| ~13 -> exponent in fp32 range.
    if (!eh) {
        const float sE = -2.8853900817779268f / TEMP[0];  // -2*log2(e)/temp
        const float p0 = __builtin_amdgcn_exp2f((acc0 + s_sp[0][v]) * sE);
        const float p1 = __builtin_amdgcn_exp2f((acc1 + s_sp[1][v]) * sE);
        const float p2 = __builtin_amdgcn_exp2f((acc2 + s_sp[2][v]) * sE);
        const float p3 = __builtin_amdgcn_exp2f((acc3 + s_sp[3][v]) * sE);
        s_prob[0][v] = p0; s_prob[1][v] = p1;
        s_prob[2][v] = p2; s_prob[3][v] = p3;
        const float r0 = wave_reduce_sum(p0);
        const float r1 = wave_reduce_sum(p1);
        const float r2 = wave_reduce_sum(p2);
        const float r3 = wave_reduce_sum(p3);
        if (ln == 0) {
            s_sum[0][wv] = r0; s_sum[1][wv] = r1;
            s_sum[2][wv] = r2; s_sum[3][wv] = r3;
        }
    }
    __syncthreads();

    // ---- phase 3: PV on unnormalized probs. 16 waves x 32 v; lane = e-quad
    {
        const float4* M4 = (const float4*)(M + (size_t)n * NV_ * NE_);
        float4 h0 = make_float4(0.f, 0.f, 0.f, 0.f);
        float4 h1 = h0, h2 = h0, h3 = h0;
        const int v0w = wv * 32;
#pragma unroll 2
        for (int vb = v0w; vb < v0w + 32; vb += 4) {
            const float4 pq0 = *(const float4*)&s_prob[0][vb];
            const float4 pq1 = *(const float4*)&s_prob[1][vb];
            const float4 pq2 = *(const float4*)&s_prob[2][vb];
            const float4 pq3 = *(const float4*)&s_prob[3][vb];
            float4 mm;
            mm = M4[(size_t)(vb + 0) * (NE_ / 4) + ln];
            FMA4(h0, pq0.x, mm); FMA4(h1, pq1.x, mm);
            FMA4(h2, pq2.x, mm); FMA4(h3, pq3.x, mm);
            mm = M4[(size_t)(vb + 1) * (NE_ / 4) + ln];
            FMA4(h0, pq0.y, mm); FMA4(h1, pq1.y, mm);
            FMA4(h2, pq2.y, mm); FMA4(h3, pq3.y, mm);
            mm = M4[(size_t)(vb + 2) * (NE_ / 4) + ln];
            FMA4(h0, pq0.z, mm); FMA4(h1, pq1.z, mm);
            FMA4(h2, pq2.z, mm); FMA4(h3, pq3.z, mm);
            mm = M4[(size_t)(vb + 3) * (NE_ / 4) + ln];
            FMA4(h0, pq0.w, mm); FMA4(h1, pq1.w, mm);
            FMA4(h2, pq2.w, mm); FMA4(h3, pq3.w, mm);
        }
        ((float4*)s_part[wv][0])[ln] = h0;
        ((float4*)s_part[wv][1])[ln] = h1;
        ((float4*)s_part[wv][2])[ln] = h2;
        ((float4*)s_part[wv][3])[ln] = h3;
    }
    __syncthreads();

    // ---- reduce 16 PV partials, fold 1/sum (softmax denom) + leaky_relu ----
    {
        const int t = tid >> 8, e = tid & 255;
        float s = 0.f;
#pragma unroll
        for (int w = 0; w < 16; ++w) s += s_part[w][t][e];
        float tot = 0.f;
#pragma unroll
        for (int w = 0; w < 8; ++w) tot += s_sum[t][w];
        const float hv = s * (1.0f / tot);
        s_heads[t][e] = (hv > 0.0f) ? hv : 0.01f * hv;
    }
    __syncthreads();

    // ---- out GEMM: thread = (q, e-quarter k, ep-quad). float4 WRT loads,
    //      wave-uniform k -> coalesced 1KB/load; 4-way e-merge via LDS ----
    {
        const int q   = tid >> 8;
        const int k   = (tid >> 6) & 3;
        const int epq = tid & 63;
        const float4* wr4 = (const float4*)WRT + epq;
        float4 a = make_float4(0.f, 0.f, 0.f, 0.f);
        const int e0g = k * 64;
#pragma unroll 8
        for (int e = e0g; e < e0g + 64; ++e) {
            const float h = s_heads[q][e];
            const float4 w4 = wr4[(size_t)e * (NE_ / 4)];
            FMA4(a, h, w4);
        }
        if (k) s_gp4[k - 1][q][epq] = a;
        __syncthreads();
        if (k == 0) {
#pragma unroll
            for (int kk = 0; kk < 3; ++kk) {
                const float4 p = s_gp4[kk][q][epq];
                a.x += p.x; a.y += p.y; a.z += p.z; a.w += p.w;
            }
            const float4 b4 = ((const float4*)BR)[epq];
            a.x += b4.x; a.y += b4.y; a.z += b4.z; a.w += b4.w;
            ((float4*)OUT)[((size_t)n * NQ_ + q0 + q) * (NE_ / 4) + epq] = a;
        }
    }
}

extern "C" void kernel_launch(void* const* d_in, const int* in_sizes, int n_in,
                              void* d_out, int out_size, void* d_ws, size_t ws_size,
                              hipStream_t stream) {
    const float* Q  = (const float*)d_in[0];
    const float* C  = (const float*)d_in[1];
    const float* M  = (const float*)d_in[2];
    const float* WL = (const float*)d_in[3];
    // d_in[4] = b_logit: softmax shift-invariant -> unused.
    const float* T  = (const float*)d_in[5];
    const float* WR = (const float*)d_in[6];
    const float* BR = (const float*)d_in[7];
    float* OUT = (float*)d_out;

    float* EC  = (float*)d_ws;                   // N*NE*NV floats (quads) = 2 MB
    float* WRT = EC + (size_t)N_B * NE_ * NV_;   // NE*NE = 256 KB

    prep_kernel<<<dim3(144), 256, 0, stream>>>(C, WR, EC, WRT);

    dim3 gf(NQ_ / QTF, N_B);
    fused_attn<<<gf, 1024, 0, stream>>>(Q, EC, WL, M, T, WRT, BR, OUT);
}